// Round 7
// baseline (187.930 us; speedup 1.0000x reference)
//
#include <hip/hip_runtime.h>
#include <hip/hip_bf16.h>

#define BS 4
#define L 2048
#define H 12
#define HD 64
#define R 16
#define HID 768
#define MARGIN 0.02f
#define FIXCAP 16384
#define FIXGRID 1024
// M = BS*L = 8192, N = 768, K = 768

typedef __attribute__((ext_vector_type(8))) short s8v;   // 8 bf16 (4 VGPRs)
typedef __attribute__((ext_vector_type(4))) float f32x4;

static __device__ __forceinline__ unsigned short f2bf_bits(float f) {
    __hip_bfloat16 h = __float2bfloat16(f);
    return *reinterpret_cast<unsigned short*>(&h);
}

// ---------------------------------------------------------------------------
__global__ void zero_cnt(int* __restrict__ cnt) { if (threadIdx.x == 0) *cnt = 0; }

// ---------------------------------------------------------------------------
// fp32 -> bf16 elementwise (hidden_states), float4 in / ushort4 out.
// Hoists the convert out of the GEMM K-loop (was 16 cvt/thread/iter there).
// ---------------------------------------------------------------------------
__global__ __launch_bounds__(256) void convert_hs(
    const float* __restrict__ in, __hip_bfloat16* __restrict__ out)
{
    int i = (blockIdx.x * 256 + threadIdx.x) * 4;
    float4 v = *(const float4*)&in[i];
    ushort4 o;
    o.x = f2bf_bits(v.x); o.y = f2bf_bits(v.y);
    o.z = f2bf_bits(v.z); o.w = f2bf_bits(v.w);
    *(ushort4*)&out[i] = o;
}

// ---------------------------------------------------------------------------
// W (k,n) fp32 -> Wt (n,k) bf16, 32x32 LDS tile transpose
// ---------------------------------------------------------------------------
__global__ __launch_bounds__(256) void transpose_wt(
    const float* __restrict__ in, __hip_bfloat16* __restrict__ out)
{
    __shared__ float s[32][33];
    const int c = threadIdx.x & 31, r8 = threadIdx.x >> 5;
    const int kt = blockIdx.x * 32, nt = blockIdx.y * 32;
#pragma unroll
    for (int rr = 0; rr < 4; ++rr) {
        int k = r8 + rr * 8;
        s[k][c] = in[(size_t)(kt + k) * HID + nt + c];
    }
    __syncthreads();
#pragma unroll
    for (int rr = 0; rr < 4; ++rr) {
        int n = r8 + rr * 8;
        out[(size_t)(nt + n) * HID + kt + c] = __float2bfloat16(s[c][n]);
    }
}

// ---------------------------------------------------------------------------
// Fused dual GEMM: bf16 MFMA 16x16x32, 128x128 tile, 4 waves of 64x64.
// blockIdx.y < 6  -> V1 tile:  +bias, relu, store bf16.
// blockIdx.y >= 6 -> K-dots:   +bias, relu, *RH, 16-lane reduce -> dots,
//                    near-threshold rows -> fixlist.
// Staging: pure bf16 float4 copies, r-major slots (writes at bank floor,
// frag ds_read_b128 2-way only = free).
// ---------------------------------------------------------------------------
__global__ __launch_bounds__(256) void gemm_fused(
    const __hip_bfloat16* __restrict__ A,    // (8192, 768) bf16
    const __hip_bfloat16* __restrict__ WtK,  // (768, 768) = K1_w^T bf16
    const __hip_bfloat16* __restrict__ WtV,  // (768, 768) = V1_w^T bf16
    const float* __restrict__ K1b,
    const float* __restrict__ V1b,
    const float* __restrict__ RH,            // (H*HD) flat
    float* __restrict__ dots,                // (BS*H, L) fp32
    int* __restrict__ fixlist,               // packed row*16+head
    int* __restrict__ fixcnt,
    __hip_bfloat16* __restrict__ C)          // (8192, 768) relu'd V1
{
    __shared__ __hip_bfloat16 As[128][40];
    __shared__ __hip_bfloat16 Bs[128][40];

    const int tid = threadIdx.x;
    const bool isV = blockIdx.y < 6;
    const int m0 = blockIdx.x * 128;
    const int n0 = (isV ? blockIdx.y : blockIdx.y - 6) * 128;
    const __hip_bfloat16* Bt = isV ? WtV : WtK;

    const int wid = tid >> 6, lane = tid & 63;
    const int quad = lane >> 4, lm = lane & 15;
    const int wm = wid & 1, wn = wid >> 1;

    f32x4 acc[4][4] = {};

    for (int k0 = 0; k0 < HID; k0 += 32) {
#pragma unroll
        for (int it = 0; it < 2; ++it) {
            int slot = tid + it * 256;            // 0..511
            int r = slot >> 2, kq = slot & 3;     // r 0..127, 8 bf16 per kq
            *(float4*)&As[r][kq * 8] =
                *(const float4*)&A[(size_t)(m0 + r) * HID + k0 + kq * 8];
        }
#pragma unroll
        for (int it = 0; it < 2; ++it) {
            int slot = tid + it * 256;
            int r = slot >> 2, kq = slot & 3;
            *(float4*)&Bs[r][kq * 8] =
                *(const float4*)&Bt[(size_t)(n0 + r) * HID + k0 + kq * 8];
        }
        __syncthreads();
        s8v af[4], bf[4];
#pragma unroll
        for (int i = 0; i < 4; ++i)
            af[i] = *(const s8v*)&As[wm * 64 + i * 16 + lm][quad * 8];
#pragma unroll
        for (int j = 0; j < 4; ++j)
            bf[j] = *(const s8v*)&Bs[wn * 64 + j * 16 + lm][quad * 8];
#pragma unroll
        for (int i = 0; i < 4; ++i)
#pragma unroll
            for (int j = 0; j < 4; ++j)
                acc[i][j] = __builtin_amdgcn_mfma_f32_16x16x32_bf16(
                    af[i], bf[j], acc[i][j], 0, 0, 0);
        __syncthreads();
    }

    if (isV) {
        // C/D layout: col = lane&15, row = quad*4 + reg  [m89/m91 verified]
#pragma unroll
        for (int i = 0; i < 4; ++i) {
            int row_b = m0 + wm * 64 + i * 16 + quad * 4;
#pragma unroll
            for (int j = 0; j < 4; ++j) {
                int col = n0 + wn * 64 + j * 16 + lm;
                float bsv = V1b[col];
#pragma unroll
                for (int reg = 0; reg < 4; ++reg) {
                    float v = acc[i][j][reg] + bsv;
                    C[(size_t)(row_b + reg) * HID + col] =
                        __float2bfloat16(fmaxf(v, 0.f));
                }
            }
        }
    } else {
        const int head = (n0 >> 6) + wn;      // wave covers one head's 64 cols
        float bj[4], rj[4];
#pragma unroll
        for (int j = 0; j < 4; ++j) {
            bj[j] = K1b[head * 64 + j * 16 + lm];
            rj[j] = RH[head * 64 + j * 16 + lm];
        }
#pragma unroll
        for (int i = 0; i < 4; ++i) {
            int row0 = m0 + wm * 64 + i * 16 + quad * 4;
#pragma unroll
            for (int reg = 0; reg < 4; ++reg) {
                float p = 0.f;
#pragma unroll
                for (int j = 0; j < 4; ++j)
                    p = fmaf(fmaxf(acc[i][j][reg] + bj[j], 0.f), rj[j], p);
                p += __shfl_xor(p, 1, 64);
                p += __shfl_xor(p, 2, 64);
                p += __shfl_xor(p, 4, 64);
                p += __shfl_xor(p, 8, 64);
                if (lm == 0) {
                    int row = row0 + reg;
                    int b = row >> 11, l = row & (L - 1);
                    dots[((b * H + head) << 11) + l] = p;
                    if (fabsf(p - 0.5f) < MARGIN) {
                        int idx = atomicAdd(fixcnt, 1);
                        if (idx < FIXCAP) fixlist[idx] = row * 16 + head;
                    }
                }
            }
        }
    }
}

// ---------------------------------------------------------------------------
// Fix-up: one block per flagged row (grid-stride over compacted list).
// Exact fp32 recompute: hs row staged in LDS, W reads coalesced over d.
// ---------------------------------------------------------------------------
__global__ __launch_bounds__(256) void fixup_kernel(
    const float* __restrict__ hs,      // (BS*L, 768) fp32
    const float* __restrict__ W,       // (768, 768) K1_w fp32
    const float* __restrict__ bias,
    const float* __restrict__ RH,
    const int* __restrict__ fixlist,
    const int* __restrict__ fixcnt,
    float* __restrict__ dots)
{
    __shared__ float hrow[HID];
    __shared__ float psum[4][64];

    const int tid = threadIdx.x;
    const int n = min(*fixcnt, FIXCAP);

    for (int item = blockIdx.x; item < n; item += FIXGRID) {
        int packed = fixlist[item];
        int row = packed >> 4, head = packed & 15;
        int b = row >> 11, l = row & (L - 1);

#pragma unroll
        for (int i = 0; i < 3; ++i)
            hrow[tid + i * 256] = hs[(size_t)row * HID + tid + i * 256];
        __syncthreads();

        const int d = tid & 63, kq = tid >> 6;
        float a0 = 0.f, a1 = 0.f;
#pragma unroll 8
        for (int i = 0; i < 96; ++i) {
            int k = kq + i * 8;
            a0 = fmaf(W[(size_t)k * HID + head * 64 + d], hrow[k], a0);
            a1 = fmaf(W[(size_t)(k + 4) * HID + head * 64 + d], hrow[k + 4], a1);
        }
        psum[kq][d] = a0 + a1;
        __syncthreads();
        if (tid < 64) {
            float v = psum[0][tid] + psum[1][tid] + psum[2][tid] +
                      psum[3][tid] + bias[head * 64 + tid];
            v = fmaxf(v, 0.f) * RH[head * 64 + tid];
#pragma unroll
            for (int s = 1; s < 64; s <<= 1) v += __shfl_xor(v, s, 64);
            if (tid == 0) dots[((size_t)(b * H + head) << 11) + l] = v;
        }
        __syncthreads();
    }
}

// ---------------------------------------------------------------------------
// Parallel rank/select scan over dots>0.5. One block per (b,h).
// ---------------------------------------------------------------------------
__global__ __launch_bounds__(256) void scan_kernel(
    const float* __restrict__ dots,   // (BS*H, L)
    short* __restrict__ fm,
    short* __restrict__ bm)
{
    __shared__ unsigned short P[L];
    __shared__ unsigned short S[L];
    __shared__ int wsum[4];

    const int bh = blockIdx.x;
    const int b = bh / H, h = bh % H;
    const int tid = threadIdx.x;
    const int base = tid * 8;
    const int lane = tid & 63, w = tid >> 6;

    int m[8], c[8];
    int run = 0;
#pragma unroll
    for (int i = 0; i < 8; ++i) {
        int l = base + i;
        m[i] = (l >= 1 && dots[((size_t)bh << 11) + l] > 0.5f) ? 1 : 0;
        run += m[i];
        c[i] = run;
    }
    int sc = run;
#pragma unroll
    for (int s = 1; s < 64; s <<= 1) {
        int v = __shfl_up(sc, s, 64);
        if (lane >= s) sc += v;
    }
    if (lane == 63) wsum[w] = sc;
    __syncthreads();
    int woff = 0;
    for (int i = 0; i < 4; ++i) if (i < w) woff += wsum[i];
    const int ex = woff + sc - run;

#pragma unroll
    for (int i = 0; i < 8; ++i) {
        int l = base + i;
        int pc = ex + c[i];
        P[l] = (unsigned short)pc;
        if (m[i]) S[pc] = (unsigned short)l;
    }
    __syncthreads();
    const int T = P[L - 1];

#pragma unroll
    for (int i = 0; i < 8; ++i) {
        int l = base + i;
        int cc = ex + c[i];
        union { unsigned short s[16]; uint4 q[2]; } uf, ub;
#pragma unroll
        for (int r = 0; r < 16; ++r)
            uf.s[r] = (cc - r >= 1) ? S[cc - r] : (unsigned short)0;
        int cp = (l >= 1) ? (int)P[l - 1] : 0;
#pragma unroll
        for (int r = 0; r < 16; ++r) {
            int j = cp + 1 + r;
            ub.s[r] = (l >= 1 && j <= T) ? S[j] : (unsigned short)0;
        }
        size_t off = ((size_t)(b * L + l) * H + h) * R;
        *(uint4*)&fm[off] = uf.q[0];
        *(uint4*)&fm[off + 8] = uf.q[1];
        *(uint4*)&bm[off] = ub.q[0];
        *(uint4*)&bm[off + 8] = ub.q[1];
    }
}

// ---------------------------------------------------------------------------
// Gather + weighted sum. 192 threads, TWO l-values per block.
// ---------------------------------------------------------------------------
__global__ __launch_bounds__(192) void gather_kernel(
    const __hip_bfloat16* __restrict__ V1,   // (8192, 768) bf16
    const short* __restrict__ fm,
    const short* __restrict__ bm,
    const float* __restrict__ bw,            // (H, 2R)
    float* __restrict__ out)                 // (8192, 768) fp32
{
    __shared__ short sidx[2][2][H][R];
    __shared__ float sw[2][H][R];

    const int bl0 = blockIdx.x * 2;
    const int b = bl0 >> 11;
    const int tid = threadIdx.x;

    for (int i = tid; i < 2 * 2 * H * R; i += 192) {
        int ls = i / (2 * H * R), rem = i % (2 * H * R);
        int dir = rem / (H * R), hr = rem % (H * R);
        int h = hr >> 4, r = hr & 15;
        const short* src = dir ? bm : fm;
        sidx[ls][dir][h][r] = src[((size_t)(bl0 + ls) * H + h) * R + r];
    }
    for (int i = tid; i < 2 * H * R; i += 192) {
        int dir = i / (H * R), hr = i % (H * R);
        int h = hr >> 4, r = hr & 15;
        sw[dir][h][r] = bw[h * (2 * R) + dir * R + r];
    }
    __syncthreads();

    const int ls = tid / 96, t = tid % 96;
    const int h = t >> 3, d8 = t & 7;
    const __hip_bfloat16* Vb = V1 + (size_t)b * L * HID;

    float a[8] = {};
#pragma unroll
    for (int slot = 0; slot < 32; ++slot) {
        int dir = slot >> 4, r = slot & 15;
        int idx = sidx[ls][dir][h][r];
        float wv = sw[dir][h][r];
        const __hip_bfloat16* p = Vb + (size_t)idx * HID + h * HD + d8 * 8;
        uint4 uv = *(const uint4*)p;
        a[0] = fmaf(wv, __uint_as_float(uv.x << 16), a[0]);
        a[1] = fmaf(wv, __uint_as_float(uv.x & 0xffff0000u), a[1]);
        a[2] = fmaf(wv, __uint_as_float(uv.y << 16), a[2]);
        a[3] = fmaf(wv, __uint_as_float(uv.y & 0xffff0000u), a[3]);
        a[4] = fmaf(wv, __uint_as_float(uv.z << 16), a[4]);
        a[5] = fmaf(wv, __uint_as_float(uv.z & 0xffff0000u), a[5]);
        a[6] = fmaf(wv, __uint_as_float(uv.w << 16), a[6]);
        a[7] = fmaf(wv, __uint_as_float(uv.w & 0xffff0000u), a[7]);
    }
    float* op = &out[(size_t)(bl0 + ls) * HID + h * HD + d8 * 8];
    float4 o0, o1;
    o0.x = a[0]; o0.y = a[1]; o0.z = a[2]; o0.w = a[3];
    o1.x = a[4]; o1.y = a[5]; o1.z = a[6]; o1.w = a[7];
    *(float4*)op = o0;
    *(float4*)(op + 4) = o1;
}

extern "C" void kernel_launch(void* const* d_in, const int* in_sizes, int n_in,
                              void* d_out, int out_size, void* d_ws, size_t ws_size,
                              hipStream_t stream) {
    const float* hs  = (const float*)d_in[0];
    const float* K1w = (const float*)d_in[1];
    const float* K1b = (const float*)d_in[2];
    const float* V1w = (const float*)d_in[3];
    const float* V1b = (const float*)d_in[4];
    const float* RH  = (const float*)d_in[5];
    const float* bw  = (const float*)d_in[6];
    float* out = (float*)d_out;

    // Abf lives in d_out (25 MB fp32 area; Abf needs 12.6 MB). Dead before
    // gather_kernel overwrites d_out — stream-serial, safe.
    __hip_bfloat16* Abf = (__hip_bfloat16*)d_out;

    // workspace layout (total ~21.7 MB)
    char* ws = (char*)d_ws;
    __hip_bfloat16* WtV = (__hip_bfloat16*)ws;                 // 1,179,648
    __hip_bfloat16* WtK = (__hip_bfloat16*)(ws + 1179648);     // 1,179,648
    __hip_bfloat16* V1  = (__hip_bfloat16*)(ws + 2359296);     // 12,582,912
    float* dots = (float*)(ws + 14942208);                     //   393,216
    short* fm   = (short*)(ws + 15335424);                     // 3,145,728
    short* bm   = (short*)(ws + 18481152);                     // 3,145,728
    int* fixlist = (int*)(ws + 21626880);                      //    65,536
    int* fixcnt  = (int*)(ws + 21692416);                      //         4

    convert_hs<<<(BS * L * HID) / (256 * 4), 256, 0, stream>>>(hs, Abf);
    transpose_wt<<<dim3(HID / 32, HID / 32), 256, 0, stream>>>(V1w, WtV);
    transpose_wt<<<dim3(HID / 32, HID / 32), 256, 0, stream>>>(K1w, WtK);
    zero_cnt<<<1, 64, 0, stream>>>(fixcnt);
    gemm_fused<<<dim3(BS * L / 128, 12), 256, 0, stream>>>(
        Abf, WtK, WtV, K1b, V1b, RH, dots, fixlist, fixcnt, V1);
    fixup_kernel<<<FIXGRID, 256, 0, stream>>>(hs, K1w, K1b, RH, fixlist, fixcnt, dots);
    scan_kernel<<<BS * H, 256, 0, stream>>>(dots, fm, bm);
    gather_kernel<<<BS * L / 2, 192, 0, stream>>>(V1, fm, bm, bw, out);
}

// Round 8
// 180.746 us; speedup vs baseline: 1.0397x; 1.0397x over previous
//
#include <hip/hip_runtime.h>
#include <hip/hip_bf16.h>

#define BS 4
#define L 2048
#define H 12
#define HD 64
#define R 16
#define HID 768
#define MARGIN 0.02f
#define FIXCAP 16384
#define FIXGRID 1024
// M = BS*L = 8192, N = 768, K = 768

typedef __attribute__((ext_vector_type(8))) short s8v;   // 8 bf16 (4 VGPRs)
typedef __attribute__((ext_vector_type(4))) float f32x4;

typedef __attribute__((address_space(1))) const void as1_void;
typedef __attribute__((address_space(3))) void as3_void;
// async global->LDS DMA, 16B/lane; LDS dest = wave-uniform base + lane*16
#define GLOAD_LDS16(g, l) \
    __builtin_amdgcn_global_load_lds((as1_void*)(g), (as3_void*)(l), 16, 0, 0)

static __device__ __forceinline__ unsigned short f2bf_bits(float f) {
    __hip_bfloat16 h = __float2bfloat16(f);
    return *reinterpret_cast<unsigned short*>(&h);
}

// ---------------------------------------------------------------------------
// fp32 -> bf16 elementwise (hidden_states); block 0 also zeroes fixcnt.
// ---------------------------------------------------------------------------
__global__ __launch_bounds__(256) void convert_hs(
    const float* __restrict__ in, __hip_bfloat16* __restrict__ out,
    int* __restrict__ fixcnt)
{
    if (blockIdx.x == 0 && threadIdx.x == 0) *fixcnt = 0;
    int i = (blockIdx.x * 256 + threadIdx.x) * 4;
    float4 v = *(const float4*)&in[i];
    ushort4 o;
    o.x = f2bf_bits(v.x); o.y = f2bf_bits(v.y);
    o.z = f2bf_bits(v.z); o.w = f2bf_bits(v.w);
    *(ushort4*)&out[i] = o;
}

// ---------------------------------------------------------------------------
// Both W (k,n) fp32 -> Wt (n,k) bf16 transposes in one dispatch (z = which).
// ---------------------------------------------------------------------------
__global__ __launch_bounds__(256) void transpose_wt2(
    const float* __restrict__ K1w, const float* __restrict__ V1w,
    __hip_bfloat16* __restrict__ WtK, __hip_bfloat16* __restrict__ WtV)
{
    const float* in = blockIdx.z ? V1w : K1w;
    __hip_bfloat16* out = blockIdx.z ? WtV : WtK;
    __shared__ float s[32][33];
    const int c = threadIdx.x & 31, r8 = threadIdx.x >> 5;
    const int kt = blockIdx.x * 32, nt = blockIdx.y * 32;
#pragma unroll
    for (int rr = 0; rr < 4; ++rr) {
        int k = r8 + rr * 8;
        s[k][c] = in[(size_t)(kt + k) * HID + nt + c];
    }
    __syncthreads();
#pragma unroll
    for (int rr = 0; rr < 4; ++rr) {
        int n = r8 + rr * 8;
        out[(size_t)(nt + n) * HID + kt + c] = __float2bfloat16(s[c][n]);
    }
}

// ---------------------------------------------------------------------------
// Fused dual GEMM: bf16 MFMA 16x16x32, 128x128 tile, 4 waves of 64x64.
// Staging via global_load_lds width=16 into unpadded [128][32] LDS with XOR
// chunk swizzle (chunk c of row r at position c^((r>>1)&3)):
//   - DMA writes lane-sequential = conflict-free
//   - frag ds_read_b128: banks 16(lm&1)+4(quad^((lm>>1)&3)) -> 2-way = free
// blockIdx.y < 6  -> V1 tile:  +bias, relu, store bf16.
// blockIdx.y >= 6 -> K-dots:   +bias, relu, *RH, 16-lane reduce -> dots,
//                    near-threshold rows -> fixlist.
// ---------------------------------------------------------------------------
__global__ __launch_bounds__(256) void gemm_fused(
    const __hip_bfloat16* __restrict__ A,    // (8192, 768) bf16
    const __hip_bfloat16* __restrict__ WtK,  // (768, 768) = K1_w^T bf16
    const __hip_bfloat16* __restrict__ WtV,  // (768, 768) = V1_w^T bf16
    const float* __restrict__ K1b,
    const float* __restrict__ V1b,
    const float* __restrict__ RH,            // (H*HD) flat
    float* __restrict__ dots,                // (BS*H, L) fp32
    int* __restrict__ fixlist,               // packed row*16+head
    int* __restrict__ fixcnt,
    __hip_bfloat16* __restrict__ C)          // (8192, 768) relu'd V1
{
    __shared__ alignas(16) __hip_bfloat16 As[128 * 32];
    __shared__ alignas(16) __hip_bfloat16 Bs[128 * 32];

    const int tid = threadIdx.x;
    const bool isV = blockIdx.y < 6;
    const int m0 = blockIdx.x * 128;
    const int n0 = (isV ? blockIdx.y : blockIdx.y - 6) * 128;
    const __hip_bfloat16* Bt = isV ? WtV : WtK;

    const int wid = tid >> 6, lane = tid & 63;
    const int quad = lane >> 4, lm = lane & 15;
    const int wm = wid & 1, wn = wid >> 1;

    // staging pointers: lane covers row rsub = lane>>2 of a 16-row chunk,
    // fetching swizzled global chunk csw (16 B) of that row's 64-B k-window.
    const int rsub = lane >> 2;
    const int csw  = (lane & 3) ^ ((lane >> 3) & 3);
    const __hip_bfloat16* gA0 =
        A + (size_t)(m0 + 32 * wid + rsub) * HID + csw * 8;
    const __hip_bfloat16* gA1 = gA0 + (size_t)16 * HID;
    const __hip_bfloat16* gB0 =
        Bt + (size_t)(n0 + 32 * wid + rsub) * HID + csw * 8;
    const __hip_bfloat16* gB1 = gB0 + (size_t)16 * HID;
    __hip_bfloat16* lA0 = &As[(32 * wid) * 32];
    __hip_bfloat16* lA1 = &As[(32 * wid + 16) * 32];
    __hip_bfloat16* lB0 = &Bs[(32 * wid) * 32];
    __hip_bfloat16* lB1 = &Bs[(32 * wid + 16) * 32];

    // frag-read swizzled base (lane-constant)
    const int fsw = (lm >> 1) & 3;
    const __hip_bfloat16* pA = &As[(wm * 64 + lm) * 32 + ((quad ^ fsw) * 8)];
    const __hip_bfloat16* pB = &Bs[(wn * 64 + lm) * 32 + ((quad ^ fsw) * 8)];

    f32x4 acc[4][4] = {};

    for (int k0 = 0; k0 < HID; k0 += 32) {
        GLOAD_LDS16(gA0, lA0);
        GLOAD_LDS16(gA1, lA1);
        GLOAD_LDS16(gB0, lB0);
        GLOAD_LDS16(gB1, lB1);
        gA0 += 32; gA1 += 32; gB0 += 32; gB1 += 32;
        __syncthreads();          // drains vmcnt (DMA complete)

        s8v af[4], bf[4];
#pragma unroll
        for (int i = 0; i < 4; ++i)
            af[i] = *(const s8v*)(pA + i * 16 * 32);
#pragma unroll
        for (int j = 0; j < 4; ++j)
            bf[j] = *(const s8v*)(pB + j * 16 * 32);
#pragma unroll
        for (int i = 0; i < 4; ++i)
#pragma unroll
            for (int j = 0; j < 4; ++j)
                acc[i][j] = __builtin_amdgcn_mfma_f32_16x16x32_bf16(
                    af[i], bf[j], acc[i][j], 0, 0, 0);
        __syncthreads();          // protect LDS from next iter's DMA
    }

    if (isV) {
        // C/D layout: col = lane&15, row = quad*4 + reg  [m89/m91 verified]
#pragma unroll
        for (int i = 0; i < 4; ++i) {
            int row_b = m0 + wm * 64 + i * 16 + quad * 4;
#pragma unroll
            for (int j = 0; j < 4; ++j) {
                int col = n0 + wn * 64 + j * 16 + lm;
                float bsv = V1b[col];
#pragma unroll
                for (int reg = 0; reg < 4; ++reg) {
                    float v = acc[i][j][reg] + bsv;
                    C[(size_t)(row_b + reg) * HID + col] =
                        __float2bfloat16(fmaxf(v, 0.f));
                }
            }
        }
    } else {
        const int head = (n0 >> 6) + wn;      // wave covers one head's 64 cols
        float bj[4], rj[4];
#pragma unroll
        for (int j = 0; j < 4; ++j) {
            bj[j] = K1b[head * 64 + j * 16 + lm];
            rj[j] = RH[head * 64 + j * 16 + lm];
        }
#pragma unroll
        for (int i = 0; i < 4; ++i) {
            int row0 = m0 + wm * 64 + i * 16 + quad * 4;
#pragma unroll
            for (int reg = 0; reg < 4; ++reg) {
                float p = 0.f;
#pragma unroll
                for (int j = 0; j < 4; ++j)
                    p = fmaf(fmaxf(acc[i][j][reg] + bj[j], 0.f), rj[j], p);
                p += __shfl_xor(p, 1, 64);
                p += __shfl_xor(p, 2, 64);
                p += __shfl_xor(p, 4, 64);
                p += __shfl_xor(p, 8, 64);
                if (lm == 0) {
                    int row = row0 + reg;
                    int b = row >> 11, l = row & (L - 1);
                    dots[((b * H + head) << 11) + l] = p;
                    if (fabsf(p - 0.5f) < MARGIN) {
                        int idx = atomicAdd(fixcnt, 1);
                        if (idx < FIXCAP) fixlist[idx] = row * 16 + head;
                    }
                }
            }
        }
    }
}

// ---------------------------------------------------------------------------
// Fix-up: one block per flagged row (grid-stride over compacted list).
// Exact fp32 recompute: hs row staged in LDS, W reads coalesced over d.
// ---------------------------------------------------------------------------
__global__ __launch_bounds__(256) void fixup_kernel(
    const float* __restrict__ hs,      // (BS*L, 768) fp32
    const float* __restrict__ W,       // (768, 768) K1_w fp32
    const float* __restrict__ bias,
    const float* __restrict__ RH,
    const int* __restrict__ fixlist,
    const int* __restrict__ fixcnt,
    float* __restrict__ dots)
{
    __shared__ float hrow[HID];
    __shared__ float psum[4][64];

    const int tid = threadIdx.x;
    const int n = min(*fixcnt, FIXCAP);

    for (int item = blockIdx.x; item < n; item += FIXGRID) {
        int packed = fixlist[item];
        int row = packed >> 4, head = packed & 15;
        int b = row >> 11, l = row & (L - 1);

#pragma unroll
        for (int i = 0; i < 3; ++i)
            hrow[tid + i * 256] = hs[(size_t)row * HID + tid + i * 256];
        __syncthreads();

        const int d = tid & 63, kq = tid >> 6;
        float a0 = 0.f, a1 = 0.f;
#pragma unroll 8
        for (int i = 0; i < 96; ++i) {
            int k = kq + i * 8;
            a0 = fmaf(W[(size_t)k * HID + head * 64 + d], hrow[k], a0);
            a1 = fmaf(W[(size_t)(k + 4) * HID + head * 64 + d], hrow[k + 4], a1);
        }
        psum[kq][d] = a0 + a1;
        __syncthreads();
        if (tid < 64) {
            float v = psum[0][tid] + psum[1][tid] + psum[2][tid] +
                      psum[3][tid] + bias[head * 64 + tid];
            v = fmaxf(v, 0.f) * RH[head * 64 + tid];
#pragma unroll
            for (int s = 1; s < 64; s <<= 1) v += __shfl_xor(v, s, 64);
            if (tid == 0) dots[((size_t)(b * H + head) << 11) + l] = v;
        }
        __syncthreads();
    }
}

// ---------------------------------------------------------------------------
// Parallel rank/select scan over dots>0.5. One block per (b,h).
// ---------------------------------------------------------------------------
__global__ __launch_bounds__(256) void scan_kernel(
    const float* __restrict__ dots,   // (BS*H, L)
    short* __restrict__ fm,
    short* __restrict__ bm)
{
    __shared__ unsigned short P[L];
    __shared__ unsigned short S[L];
    __shared__ int wsum[4];

    const int bh = blockIdx.x;
    const int b = bh / H, h = bh % H;
    const int tid = threadIdx.x;
    const int base = tid * 8;
    const int lane = tid & 63, w = tid >> 6;

    int m[8], c[8];
    int run = 0;
#pragma unroll
    for (int i = 0; i < 8; ++i) {
        int l = base + i;
        m[i] = (l >= 1 && dots[((size_t)bh << 11) + l] > 0.5f) ? 1 : 0;
        run += m[i];
        c[i] = run;
    }
    int sc = run;
#pragma unroll
    for (int s = 1; s < 64; s <<= 1) {
        int v = __shfl_up(sc, s, 64);
        if (lane >= s) sc += v;
    }
    if (lane == 63) wsum[w] = sc;
    __syncthreads();
    int woff = 0;
    for (int i = 0; i < 4; ++i) if (i < w) woff += wsum[i];
    const int ex = woff + sc - run;

#pragma unroll
    for (int i = 0; i < 8; ++i) {
        int l = base + i;
        int pc = ex + c[i];
        P[l] = (unsigned short)pc;
        if (m[i]) S[pc] = (unsigned short)l;
    }
    __syncthreads();
    const int T = P[L - 1];

#pragma unroll
    for (int i = 0; i < 8; ++i) {
        int l = base + i;
        int cc = ex + c[i];
        union { unsigned short s[16]; uint4 q[2]; } uf, ub;
#pragma unroll
        for (int r = 0; r < 16; ++r)
            uf.s[r] = (cc - r >= 1) ? S[cc - r] : (unsigned short)0;
        int cp = (l >= 1) ? (int)P[l - 1] : 0;
#pragma unroll
        for (int r = 0; r < 16; ++r) {
            int j = cp + 1 + r;
            ub.s[r] = (l >= 1 && j <= T) ? S[j] : (unsigned short)0;
        }
        size_t off = ((size_t)(b * L + l) * H + h) * R;
        *(uint4*)&fm[off] = uf.q[0];
        *(uint4*)&fm[off + 8] = uf.q[1];
        *(uint4*)&bm[off] = ub.q[0];
        *(uint4*)&bm[off + 8] = ub.q[1];
    }
}

// ---------------------------------------------------------------------------
// Gather + weighted sum. 192 threads, TWO l-values per block.
// ---------------------------------------------------------------------------
__global__ __launch_bounds__(192) void gather_kernel(
    const __hip_bfloat16* __restrict__ V1,   // (8192, 768) bf16
    const short* __restrict__ fm,
    const short* __restrict__ bm,
    const float* __restrict__ bw,            // (H, 2R)
    float* __restrict__ out)                 // (8192, 768) fp32
{
    __shared__ short sidx[2][2][H][R];
    __shared__ float sw[2][H][R];

    const int bl0 = blockIdx.x * 2;
    const int b = bl0 >> 11;
    const int tid = threadIdx.x;

    for (int i = tid; i < 2 * 2 * H * R; i += 192) {
        int ls = i / (2 * H * R), rem = i % (2 * H * R);
        int dir = rem / (H * R), hr = rem % (H * R);
        int h = hr >> 4, r = hr & 15;
        const short* src = dir ? bm : fm;
        sidx[ls][dir][h][r] = src[((size_t)(bl0 + ls) * H + h) * R + r];
    }
    for (int i = tid; i < 2 * H * R; i += 192) {
        int dir = i / (H * R), hr = i % (H * R);
        int h = hr >> 4, r = hr & 15;
        sw[dir][h][r] = bw[h * (2 * R) + dir * R + r];
    }
    __syncthreads();

    const int ls = tid / 96, t = tid % 96;
    const int h = t >> 3, d8 = t & 7;
    const __hip_bfloat16* Vb = V1 + (size_t)b * L * HID;

    float a[8] = {};
#pragma unroll
    for (int slot = 0; slot < 32; ++slot) {
        int dir = slot >> 4, r = slot & 15;
        int idx = sidx[ls][dir][h][r];
        float wv = sw[dir][h][r];
        const __hip_bfloat16* p = Vb + (size_t)idx * HID + h * HD + d8 * 8;
        uint4 uv = *(const uint4*)p;
        a[0] = fmaf(wv, __uint_as_float(uv.x << 16), a[0]);
        a[1] = fmaf(wv, __uint_as_float(uv.x & 0xffff0000u), a[1]);
        a[2] = fmaf(wv, __uint_as_float(uv.y << 16), a[2]);
        a[3] = fmaf(wv, __uint_as_float(uv.y & 0xffff0000u), a[3]);
        a[4] = fmaf(wv, __uint_as_float(uv.z << 16), a[4]);
        a[5] = fmaf(wv, __uint_as_float(uv.z & 0xffff0000u), a[5]);
        a[6] = fmaf(wv, __uint_as_float(uv.w << 16), a[6]);
        a[7] = fmaf(wv, __uint_as_float(uv.w & 0xffff0000u), a[7]);
    }
    float* op = &out[(size_t)(bl0 + ls) * HID + h * HD + d8 * 8];
    float4 o0, o1;
    o0.x = a[0]; o0.y = a[1]; o0.z = a[2]; o0.w = a[3];
    o1.x = a[4]; o1.y = a[5]; o1.z = a[6]; o1.w = a[7];
    *(float4*)op = o0;
    *(float4*)(op + 4) = o1;
}

extern "C" void kernel_launch(void* const* d_in, const int* in_sizes, int n_in,
                              void* d_out, int out_size, void* d_ws, size_t ws_size,
                              hipStream_t stream) {
    const float* hs  = (const float*)d_in[0];
    const float* K1w = (const float*)d_in[1];
    const float* K1b = (const float*)d_in[2];
    const float* V1w = (const float*)d_in[3];
    const float* V1b = (const float*)d_in[4];
    const float* RH  = (const float*)d_in[5];
    const float* bw  = (const float*)d_in[6];
    float* out = (float*)d_out;

    // Abf lives in d_out (25 MB fp32 area; Abf needs 12.6 MB). Dead before
    // gather_kernel overwrites d_out — stream-serial, safe.
    __hip_bfloat16* Abf = (__hip_bfloat16*)d_out;

    // workspace layout (total ~21.7 MB)
    char* ws = (char*)d_ws;
    __hip_bfloat16* WtV = (__hip_bfloat16*)ws;                 // 1,179,648
    __hip_bfloat16* WtK = (__hip_bfloat16*)(ws + 1179648);     // 1,179,648
    __hip_bfloat16* V1  = (__hip_bfloat16*)(ws + 2359296);     // 12,582,912
    float* dots = (float*)(ws + 14942208);                     //   393,216
    short* fm   = (short*)(ws + 15335424);                     // 3,145,728
    short* bm   = (short*)(ws + 18481152);                     // 3,145,728
    int* fixlist = (int*)(ws + 21626880);                      //    65,536
    int* fixcnt  = (int*)(ws + 21692416);                      //         4

    convert_hs<<<(BS * L * HID) / (256 * 4), 256, 0, stream>>>(hs, Abf, fixcnt);
    transpose_wt2<<<dim3(HID / 32, HID / 32, 2), 256, 0, stream>>>(K1w, V1w, WtK, WtV);
    gemm_fused<<<dim3(BS * L / 128, 12), 256, 0, stream>>>(
        Abf, WtK, WtV, K1b, V1b, RH, dots, fixlist, fixcnt, V1);
    fixup_kernel<<<FIXGRID, 256, 0, stream>>>(hs, K1w, K1b, RH, fixlist, fixcnt, dots);
    scan_kernel<<<BS * H, 256, 0, stream>>>(dots, fm, bm);
    gather_kernel<<<BS * L / 2, 192, 0, stream>>>(V1, fm, bm, bw, out);
}

// Round 9
// 170.054 us; speedup vs baseline: 1.1051x; 1.0629x over previous
//
#include <hip/hip_runtime.h>
#include <hip/hip_bf16.h>

#define BS 4
#define L 2048
#define H 12
#define HD 64
#define R 16
#define HID 768
#define MARGIN 0.02f
#define FIXCAP 16384
#define FIXGRID 1024
// M = BS*L = 8192, N = 768, K = 768

typedef __attribute__((ext_vector_type(8))) short s8v;   // 8 bf16 (4 VGPRs)
typedef __attribute__((ext_vector_type(4))) float f32x4;

typedef __attribute__((address_space(1))) const void as1_void;
typedef __attribute__((address_space(3))) void as3_void;
// async global->LDS DMA, 16B/lane; LDS dest = wave-uniform base + lane*16
#define GLOAD_LDS16(g, l) \
    __builtin_amdgcn_global_load_lds((as1_void*)(g), (as3_void*)(l), 16, 0, 0)

static __device__ __forceinline__ unsigned short f2bf_bits(float f) {
    __hip_bfloat16 h = __float2bfloat16(f);
    return *reinterpret_cast<unsigned short*>(&h);
}

// ---------------------------------------------------------------------------
// fp32 -> bf16 elementwise (hidden_states); block 0 also zeroes fixcnt.
// ---------------------------------------------------------------------------
__global__ __launch_bounds__(256) void convert_hs(
    const float* __restrict__ in, __hip_bfloat16* __restrict__ out,
    int* __restrict__ fixcnt)
{
    if (blockIdx.x == 0 && threadIdx.x == 0) *fixcnt = 0;
    int i = (blockIdx.x * 256 + threadIdx.x) * 4;
    float4 v = *(const float4*)&in[i];
    ushort4 o;
    o.x = f2bf_bits(v.x); o.y = f2bf_bits(v.y);
    o.z = f2bf_bits(v.z); o.w = f2bf_bits(v.w);
    *(ushort4*)&out[i] = o;
}

// ---------------------------------------------------------------------------
// Both W (k,n) fp32 -> Wt (n,k) bf16 transposes in one dispatch (z = which).
// ---------------------------------------------------------------------------
__global__ __launch_bounds__(256) void transpose_wt2(
    const float* __restrict__ K1w, const float* __restrict__ V1w,
    __hip_bfloat16* __restrict__ WtK, __hip_bfloat16* __restrict__ WtV)
{
    const float* in = blockIdx.z ? V1w : K1w;
    __hip_bfloat16* out = blockIdx.z ? WtV : WtK;
    __shared__ float s[32][33];
    const int c = threadIdx.x & 31, r8 = threadIdx.x >> 5;
    const int kt = blockIdx.x * 32, nt = blockIdx.y * 32;
#pragma unroll
    for (int rr = 0; rr < 4; ++rr) {
        int k = r8 + rr * 8;
        s[k][c] = in[(size_t)(kt + k) * HID + nt + c];
    }
    __syncthreads();
#pragma unroll
    for (int rr = 0; rr < 4; ++rr) {
        int n = r8 + rr * 8;
        out[(size_t)(nt + n) * HID + kt + c] = __float2bfloat16(s[c][n]);
    }
}

// ---------------------------------------------------------------------------
// Fused dual GEMM, BK=64 (12 K-iters, 32 MFMA per barrier pair).
// Staging via global_load_lds width=16 into unpadded [128][64] LDS with XOR
// chunk swizzle (16B chunk c of row r stored at position c^(r&7)):
//   DMA writes lane-sequential (conflict-free); frag ds_read_b128 2-way = free.
// blockIdx.y < 6  -> V1 tile; blockIdx.y >= 6 -> K-dots tile.
// ---------------------------------------------------------------------------
__global__ __launch_bounds__(256) void gemm_fused(
    const __hip_bfloat16* __restrict__ A,    // (8192, 768) bf16
    const __hip_bfloat16* __restrict__ WtK,  // (768, 768) = K1_w^T bf16
    const __hip_bfloat16* __restrict__ WtV,  // (768, 768) = V1_w^T bf16
    const float* __restrict__ K1b,
    const float* __restrict__ V1b,
    const float* __restrict__ RH,            // (H*HD) flat
    float* __restrict__ dots,                // (BS*H, L) fp32
    int* __restrict__ fixlist,               // packed row*16+head
    int* __restrict__ fixcnt,
    __hip_bfloat16* __restrict__ C)          // (8192, 768) relu'd V1
{
    __shared__ alignas(16) __hip_bfloat16 As[128 * 64];
    __shared__ alignas(16) __hip_bfloat16 Bs[128 * 64];

    const int tid = threadIdx.x;
    const bool isV = blockIdx.y < 6;
    const int m0 = blockIdx.x * 128;
    const int n0 = (isV ? blockIdx.y : blockIdx.y - 6) * 128;
    const __hip_bfloat16* Bt = isV ? WtV : WtK;

    const int wid = tid >> 6, lane = tid & 63;
    const int quad = lane >> 4, lm = lane & 15;
    const int wm = wid & 1, wn = wid >> 1;

    // staging: each DMA covers 8 rows (64 lanes x 16B / 128B row).
    // lane -> row (lane>>3) of the 8-row group, dest chunk (lane&7);
    // source chunk = (lane&7) ^ ((lane>>3)&7)  (row base multiple of 8).
    const int srow = lane >> 3;
    const int schk = (lane & 7) ^ ((lane >> 3) & 7);
    const __hip_bfloat16* gA =
        A + (size_t)(m0 + 32 * wid + srow) * HID + schk * 8;
    const __hip_bfloat16* gB =
        Bt + (size_t)(n0 + 32 * wid + srow) * HID + schk * 8;
    __hip_bfloat16* lA = &As[(32 * wid) * 64];
    __hip_bfloat16* lB = &Bs[(32 * wid) * 64];

    // frag-read swizzled pointers (row r -> r&7 == lm&7, constant per lane)
    const int s7 = lm & 7;
    const __hip_bfloat16* pA0 = &As[(wm * 64 + lm) * 64 + ((quad ^ s7) * 8)];
    const __hip_bfloat16* pA1 = &As[(wm * 64 + lm) * 64 + (((4 + quad) ^ s7) * 8)];
    const __hip_bfloat16* pB0 = &Bs[(wn * 64 + lm) * 64 + ((quad ^ s7) * 8)];
    const __hip_bfloat16* pB1 = &Bs[(wn * 64 + lm) * 64 + (((4 + quad) ^ s7) * 8)];

    f32x4 acc[4][4] = {};

    for (int k0 = 0; k0 < HID; k0 += 64) {
#pragma unroll
        for (int d = 0; d < 4; ++d) {
            GLOAD_LDS16(gA + (size_t)(8 * d) * HID, lA + (8 * d) * 64);
            GLOAD_LDS16(gB + (size_t)(8 * d) * HID, lB + (8 * d) * 64);
        }
        gA += 64; gB += 64;
        __syncthreads();          // drains vmcnt (DMA complete)

        s8v af[4], bf[4];
#pragma unroll
        for (int i = 0; i < 4; ++i) af[i] = *(const s8v*)(pA0 + i * 16 * 64);
#pragma unroll
        for (int j = 0; j < 4; ++j) bf[j] = *(const s8v*)(pB0 + j * 16 * 64);
#pragma unroll
        for (int i = 0; i < 4; ++i)
#pragma unroll
            for (int j = 0; j < 4; ++j)
                acc[i][j] = __builtin_amdgcn_mfma_f32_16x16x32_bf16(
                    af[i], bf[j], acc[i][j], 0, 0, 0);
#pragma unroll
        for (int i = 0; i < 4; ++i) af[i] = *(const s8v*)(pA1 + i * 16 * 64);
#pragma unroll
        for (int j = 0; j < 4; ++j) bf[j] = *(const s8v*)(pB1 + j * 16 * 64);
#pragma unroll
        for (int i = 0; i < 4; ++i)
#pragma unroll
            for (int j = 0; j < 4; ++j)
                acc[i][j] = __builtin_amdgcn_mfma_f32_16x16x32_bf16(
                    af[i], bf[j], acc[i][j], 0, 0, 0);
        __syncthreads();          // protect LDS from next iter's DMA
    }

    if (isV) {
        // C/D layout: col = lane&15, row = quad*4 + reg  [m89/m91 verified]
#pragma unroll
        for (int i = 0; i < 4; ++i) {
            int row_b = m0 + wm * 64 + i * 16 + quad * 4;
#pragma unroll
            for (int j = 0; j < 4; ++j) {
                int col = n0 + wn * 64 + j * 16 + lm;
                float bsv = V1b[col];
#pragma unroll
                for (int reg = 0; reg < 4; ++reg) {
                    float v = acc[i][j][reg] + bsv;
                    C[(size_t)(row_b + reg) * HID + col] =
                        __float2bfloat16(fmaxf(v, 0.f));
                }
            }
        }
    } else {
        const int head = (n0 >> 6) + wn;      // wave covers one head's 64 cols
        float bj[4], rj[4];
#pragma unroll
        for (int j = 0; j < 4; ++j) {
            bj[j] = K1b[head * 64 + j * 16 + lm];
            rj[j] = RH[head * 64 + j * 16 + lm];
        }
#pragma unroll
        for (int i = 0; i < 4; ++i) {
            int row0 = m0 + wm * 64 + i * 16 + quad * 4;
#pragma unroll
            for (int reg = 0; reg < 4; ++reg) {
                float p = 0.f;
#pragma unroll
                for (int j = 0; j < 4; ++j)
                    p = fmaf(fmaxf(acc[i][j][reg] + bj[j], 0.f), rj[j], p);
                p += __shfl_xor(p, 1, 64);
                p += __shfl_xor(p, 2, 64);
                p += __shfl_xor(p, 4, 64);
                p += __shfl_xor(p, 8, 64);
                if (lm == 0) {
                    int row = row0 + reg;
                    int b = row >> 11, l = row & (L - 1);
                    dots[((b * H + head) << 11) + l] = p;
                    if (fabsf(p - 0.5f) < MARGIN) {
                        int idx = atomicAdd(fixcnt, 1);
                        if (idx < FIXCAP) fixlist[idx] = row * 16 + head;
                    }
                }
            }
        }
    }
}

// ---------------------------------------------------------------------------
// Fix-up: one block per flagged row (grid-stride over compacted list).
// ---------------------------------------------------------------------------
__global__ __launch_bounds__(256) void fixup_kernel(
    const float* __restrict__ hs,      // (BS*L, 768) fp32
    const float* __restrict__ W,       // (768, 768) K1_w fp32
    const float* __restrict__ bias,
    const float* __restrict__ RH,
    const int* __restrict__ fixlist,
    const int* __restrict__ fixcnt,
    float* __restrict__ dots)
{
    __shared__ float hrow[HID];
    __shared__ float psum[4][64];

    const int tid = threadIdx.x;
    const int n = min(*fixcnt, FIXCAP);

    for (int item = blockIdx.x; item < n; item += FIXGRID) {
        int packed = fixlist[item];
        int row = packed >> 4, head = packed & 15;
        int b = row >> 11, l = row & (L - 1);

#pragma unroll
        for (int i = 0; i < 3; ++i)
            hrow[tid + i * 256] = hs[(size_t)row * HID + tid + i * 256];
        __syncthreads();

        const int d = tid & 63, kq = tid >> 6;
        float a0 = 0.f, a1 = 0.f;
#pragma unroll 8
        for (int i = 0; i < 96; ++i) {
            int k = kq + i * 8;
            a0 = fmaf(W[(size_t)k * HID + head * 64 + d], hrow[k], a0);
            a1 = fmaf(W[(size_t)(k + 4) * HID + head * 64 + d], hrow[k + 4], a1);
        }
        psum[kq][d] = a0 + a1;
        __syncthreads();
        if (tid < 64) {
            float v = psum[0][tid] + psum[1][tid] + psum[2][tid] +
                      psum[3][tid] + bias[head * 64 + tid];
            v = fmaxf(v, 0.f) * RH[head * 64 + tid];
#pragma unroll
            for (int s = 1; s < 64; s <<= 1) v += __shfl_xor(v, s, 64);
            if (tid == 0) dots[((size_t)(b * H + head) << 11) + l] = v;
        }
        __syncthreads();
    }
}

// ---------------------------------------------------------------------------
// Scan v3: rank/select tables only.
//   Pg[bh][l] = # valid indices in [1..l];  Sg[bh][j] = j-th valid index.
// (fm/bm never materialized — gather reconstructs from P,S.)
// ---------------------------------------------------------------------------
__global__ __launch_bounds__(256) void scan_kernel(
    const float* __restrict__ dots,   // (BS*H, L)
    unsigned short* __restrict__ Pg,  // (BS*H, L)
    unsigned short* __restrict__ Sg)  // (BS*H, L), 1-based, [1..T]
{
    __shared__ int wsum[4];
    const int bh = blockIdx.x;
    const int tid = threadIdx.x;
    const int base = tid * 8;
    const int lane = tid & 63, w = tid >> 6;

    int m[8], c[8];
    int run = 0;
#pragma unroll
    for (int i = 0; i < 8; ++i) {
        int l = base + i;
        m[i] = (l >= 1 && dots[((size_t)bh << 11) + l] > 0.5f) ? 1 : 0;
        run += m[i];
        c[i] = run;
    }
    int sc = run;
#pragma unroll
    for (int s = 1; s < 64; s <<= 1) {
        int v = __shfl_up(sc, s, 64);
        if (lane >= s) sc += v;
    }
    if (lane == 63) wsum[w] = sc;
    __syncthreads();
    int woff = 0;
    for (int i = 0; i < 4; ++i) if (i < w) woff += wsum[i];
    const int ex = woff + sc - run;

    union { unsigned short s[8]; uint4 q; } up;
#pragma unroll
    for (int i = 0; i < 8; ++i) {
        int pc = ex + c[i];
        up.s[i] = (unsigned short)pc;
        if (m[i]) Sg[((size_t)bh << 11) + pc] = (unsigned short)(base + i);
    }
    *(uint4*)&Pg[((size_t)bh << 11) + base] = up.q;
}

// ---------------------------------------------------------------------------
// Gather v3: block = (ltile of 128, bh). All indices for the tile lie in the
// contiguous S-range [a..b] (<=158 rows) -> stage those V1 row-slices (128 B
// each) + the row-0 slice into LDS once; compute fm/bm slots from P on the
// fly. Global traffic ~20 KB/block (~16 MB total vs 402 MB direct).
// ---------------------------------------------------------------------------
__global__ __launch_bounds__(256) void gather_kernel(
    const __hip_bfloat16* __restrict__ V1,   // (8192, 768) bf16
    const unsigned short* __restrict__ Pg,
    const unsigned short* __restrict__ Sg,
    const float* __restrict__ bw,            // (H, 2R)
    float* __restrict__ out)                 // (8192, 768) fp32
{
    __shared__ __hip_bfloat16 Vs[161 * 72];  // slot pitch 144 B (16B aligned)
    __shared__ unsigned short Ptile[129];    // P[l0-1 .. l0+127]
    __shared__ float sw[2 * R];
    __shared__ int sT;

    const int bh = blockIdx.y;
    const int b = bh / H, h = bh % H;
    const int l0 = blockIdx.x * 128;
    const int tid = threadIdx.x;

    if (tid < 129) {
        int l = l0 - 1 + tid;
        Ptile[tid] = (l >= 0) ? Pg[((size_t)bh << 11) + l] : (unsigned short)0;
    } else if (tid < 129 + 2 * R) {
        sw[tid - 129] = bw[h * (2 * R) + (tid - 129)];
    } else if (tid == 200) {
        sT = Pg[((size_t)bh << 11) + (L - 1)];
    }
    __syncthreads();

    const int T = sT;
    const int a = max(1, (int)Ptile[1] - (R - 1));
    const int bj = min(T, (int)Ptile[127] + R);
    const int nr = max(0, bj - a + 1);       // <= 158

    // stage: slot 0 = V1[b,0] slice; slots 1..nr = S[a..b] slices
    const __hip_bfloat16* Vbase = V1 + (size_t)b * L * HID + h * HD;
    for (int it = tid; it < (nr + 1) * 8; it += 256) {
        int slot = it >> 3, oct = it & 7;
        int row = slot ? (int)Sg[((size_t)bh << 11) + a + slot - 1] : 0;
        *(uint4*)&Vs[slot * 72 + oct * 8] =
            *(const uint4*)&Vbase[(size_t)row * HID + oct * 8];
    }
    __syncthreads();

    const int d8 = tid & 7, lg = tid >> 3;   // lg 0..31

#pragma unroll
    for (int li = 0; li < 4; ++li) {
        int ll = lg + 32 * li;               // 0..127
        int l = l0 + ll;
        int Pl = Ptile[1 + ll], Plm1 = Ptile[ll];
        bool lpos = (l >= 1);
        float acc0 = 0.f, acc1 = 0.f, acc2 = 0.f, acc3 = 0.f;
        float acc4 = 0.f, acc5 = 0.f, acc6 = 0.f, acc7 = 0.f;
#pragma unroll
        for (int r = 0; r < 2 * R; ++r) {
            int j, ok;
            if (r < R) { j = Pl - r;           ok = lpos && (j >= 1); }
            else       { j = Plm1 + 1 + (r - R); ok = lpos && (j <= T); }
            int slot = ok ? (j - a + 1) : 0;
            float wv = sw[r];
            uint4 uv = *(const uint4*)&Vs[slot * 72 + d8 * 8];
            acc0 = fmaf(wv, __uint_as_float(uv.x << 16), acc0);
            acc1 = fmaf(wv, __uint_as_float(uv.x & 0xffff0000u), acc1);
            acc2 = fmaf(wv, __uint_as_float(uv.y << 16), acc2);
            acc3 = fmaf(wv, __uint_as_float(uv.y & 0xffff0000u), acc3);
            acc4 = fmaf(wv, __uint_as_float(uv.z << 16), acc4);
            acc5 = fmaf(wv, __uint_as_float(uv.z & 0xffff0000u), acc5);
            acc6 = fmaf(wv, __uint_as_float(uv.w << 16), acc6);
            acc7 = fmaf(wv, __uint_as_float(uv.w & 0xffff0000u), acc7);
        }
        float* op = &out[((size_t)b * L + l) * HID + h * HD + d8 * 8];
        float4 o0, o1;
        o0.x = acc0; o0.y = acc1; o0.z = acc2; o0.w = acc3;
        o1.x = acc4; o1.y = acc5; o1.z = acc6; o1.w = acc7;
        *(float4*)op = o0;
        *(float4*)(op + 4) = o1;
    }
}

extern "C" void kernel_launch(void* const* d_in, const int* in_sizes, int n_in,
                              void* d_out, int out_size, void* d_ws, size_t ws_size,
                              hipStream_t stream) {
    const float* hs  = (const float*)d_in[0];
    const float* K1w = (const float*)d_in[1];
    const float* K1b = (const float*)d_in[2];
    const float* V1w = (const float*)d_in[3];
    const float* V1b = (const float*)d_in[4];
    const float* RH  = (const float*)d_in[5];
    const float* bw  = (const float*)d_in[6];
    float* out = (float*)d_out;

    // Abf lives in d_out (25 MB fp32 area; Abf needs 12.6 MB). Dead before
    // gather_kernel overwrites d_out — stream-serial, safe.
    __hip_bfloat16* Abf = (__hip_bfloat16*)d_out;

    // workspace layout (total ~15.8 MB)
    char* ws = (char*)d_ws;
    __hip_bfloat16* WtV = (__hip_bfloat16*)ws;                 // 1,179,648
    __hip_bfloat16* WtK = (__hip_bfloat16*)(ws + 1179648);     // 1,179,648
    __hip_bfloat16* V1  = (__hip_bfloat16*)(ws + 2359296);     // 12,582,912
    float* dots = (float*)(ws + 14942208);                     //   393,216
    unsigned short* Pg = (unsigned short*)(ws + 15335424);     //   196,608
    unsigned short* Sg = (unsigned short*)(ws + 15532032);     //   196,608
    int* fixlist = (int*)(ws + 15728640);                      //    65,536
    int* fixcnt  = (int*)(ws + 15794176);                      //         4

    convert_hs<<<(BS * L * HID) / (256 * 4), 256, 0, stream>>>(hs, Abf, fixcnt);
    transpose_wt2<<<dim3(HID / 32, HID / 32, 2), 256, 0, stream>>>(K1w, V1w, WtK, WtV);
    gemm_fused<<<dim3(BS * L / 128, 12), 256, 0, stream>>>(
        Abf, WtK, WtV, K1b, V1b, RH, dots, fixlist, fixcnt, V1);
    fixup_kernel<<<FIXGRID, 256, 0, stream>>>(hs, K1w, K1b, RH, fixlist, fixcnt, dots);
    scan_kernel<<<BS * H, 256, 0, stream>>>(dots, Pg, Sg);
    gather_kernel<<<dim3(L / 128, BS * H), 256, 0, stream>>>(V1, Pg, Sg, bw, out);
}

// Round 10
// 164.547 us; speedup vs baseline: 1.1421x; 1.0335x over previous
//
#include <hip/hip_runtime.h>
#include <hip/hip_bf16.h>

#define BS 4
#define L 2048
#define H 12
#define HD 64
#define R 16
#define HID 768
#define MARGIN 0.02f
#define FIXCAP 16384
#define FIXGRID 1024
// M = BS*L = 8192, N = 768, K = 768

typedef __attribute__((ext_vector_type(8))) short s8v;   // 8 bf16 (4 VGPRs)
typedef __attribute__((ext_vector_type(4))) float f32x4;

static __device__ __forceinline__ unsigned short f2bf_bits(float f) {
    __hip_bfloat16 h = __float2bfloat16(f);
    return *reinterpret_cast<unsigned short*>(&h);
}

// ---------------------------------------------------------------------------
// Prep: both W (k,n) fp32 -> Wt (n,k) bf16 transposes; block 0 zeroes fixcnt.
// One launch (grid 24*24*2 flattened).
// ---------------------------------------------------------------------------
__global__ __launch_bounds__(256) void prep_kernel(
    const float* __restrict__ K1w, const float* __restrict__ V1w,
    __hip_bfloat16* __restrict__ WtK, __hip_bfloat16* __restrict__ WtV,
    int* __restrict__ fixcnt)
{
    if (blockIdx.x == 0 && threadIdx.x == 0) *fixcnt = 0;
    const int t = blockIdx.x;
    const int z = t / 576, rem = t % 576;
    const float* in = z ? V1w : K1w;
    __hip_bfloat16* out = z ? WtV : WtK;
    __shared__ float s[32][33];
    const int c = threadIdx.x & 31, r8 = threadIdx.x >> 5;
    const int kt = (rem / 24) * 32, nt = (rem % 24) * 32;
#pragma unroll
    for (int rr = 0; rr < 4; ++rr) {
        int k = r8 + rr * 8;
        s[k][c] = in[(size_t)(kt + k) * HID + nt + c];
    }
    __syncthreads();
#pragma unroll
    for (int rr = 0; rr < 4; ++rr) {
        int n = r8 + rr * 8;
        out[(size_t)(nt + n) * HID + kt + c] = __float2bfloat16(s[c][n]);
    }
}

// ---------------------------------------------------------------------------
// Fused dual GEMM v4: bf16 MFMA 16x16x32, 128x128 tile, BK=32, register
// double-buffer prefetch. Per iter: cvt+ds_write tile k -> barrier -> issue
// tile k+1 global loads (consumed next iter; vmcnt wait lands after MFMAs)
// -> ds_read frags -> 16 MFMA -> barrier. A is read fp32 and converted
// in-register (no separate convert pass / buffer).
// LDS layout: unpadded [128][32] bf16, XOR chunk swizzle p = c ^ ((r>>1)&3)
// (writes 2-way = free; frag ds_read_b128 2-way = free; validated R8: 0
// SQ_LDS_BANK_CONFLICT).
// blockIdx.y < 6 -> V1 tile; >= 6 -> K-dots tile (+RH reduce, fixlist).
// ---------------------------------------------------------------------------
__global__ __launch_bounds__(256) void gemm_fused(
    const float* __restrict__ A,             // (8192, 768) fp32 hs
    const __hip_bfloat16* __restrict__ WtK,  // (768, 768) = K1_w^T bf16
    const __hip_bfloat16* __restrict__ WtV,  // (768, 768) = V1_w^T bf16
    const float* __restrict__ K1b,
    const float* __restrict__ V1b,
    const float* __restrict__ RH,            // (H*HD) flat
    float* __restrict__ dots,                // (BS*H, L) fp32
    int* __restrict__ fixlist,               // packed row*16+head
    int* __restrict__ fixcnt,
    __hip_bfloat16* __restrict__ C)          // (8192, 768) relu'd V1
{
    __shared__ alignas(16) __hip_bfloat16 As[128 * 32];
    __shared__ alignas(16) __hip_bfloat16 Bs[128 * 32];

    const int tid = threadIdx.x;
    const bool isV = blockIdx.y < 6;
    const int m0 = blockIdx.x * 128;
    const int n0 = (isV ? blockIdx.y : blockIdx.y - 6) * 128;
    const __hip_bfloat16* Bt = isV ? WtV : WtK;

    const int wid = tid >> 6, lane = tid & 63;
    const int quad = lane >> 4, lm = lane & 15;
    const int wm = wid & 1, wn = wid >> 1;

    // two staging slots per thread per matrix: slot s -> row s>>2, chunk s&3,
    // stored at swizzled chunk position p = c ^ ((r>>1)&3)
    const int r0 = tid >> 2,        c0 = tid & 3;
    const int r1 = (tid + 256) >> 2, c1 = tid & 3;
    const int p0 = c0 ^ ((r0 >> 1) & 3);
    const int p1 = c1 ^ ((r1 >> 1) & 3);

    const float* gA0 = A + (size_t)(m0 + r0) * HID + c0 * 8;
    const float* gA1 = A + (size_t)(m0 + r1) * HID + c1 * 8;
    const __hip_bfloat16* gB0 = Bt + (size_t)(n0 + r0) * HID + c0 * 8;
    const __hip_bfloat16* gB1 = Bt + (size_t)(n0 + r1) * HID + c1 * 8;
    uint4* wA0 = (uint4*)&As[r0 * 32 + p0 * 8];
    uint4* wA1 = (uint4*)&As[r1 * 32 + p1 * 8];
    uint4* wB0 = (uint4*)&Bs[r0 * 32 + p0 * 8];
    uint4* wB1 = (uint4*)&Bs[r1 * 32 + p1 * 8];

    // frag-read swizzled pointers (validated R8)
    const int fsw = (lm >> 1) & 3;
    const __hip_bfloat16* pA = &As[(wm * 64 + lm) * 32 + ((quad ^ fsw) * 8)];
    const __hip_bfloat16* pB = &Bs[(wn * 64 + lm) * 32 + ((quad ^ fsw) * 8)];

    f32x4 acc[4][4] = {};

    // prologue: load tile 0
    float4 a00 = *(const float4*)gA0, a01 = *(const float4*)(gA0 + 4);
    float4 a10 = *(const float4*)gA1, a11 = *(const float4*)(gA1 + 4);
    uint4  b0  = *(const uint4*)gB0,  b1  = *(const uint4*)gB1;
    gA0 += 32; gA1 += 32; gB0 += 32; gB1 += 32;

    for (int it = 0; it < HID / 32; ++it) {
        // convert + write tile `it`
        union { unsigned short s[8]; uint4 v; } u0, u1;
        u0.s[0] = f2bf_bits(a00.x); u0.s[1] = f2bf_bits(a00.y);
        u0.s[2] = f2bf_bits(a00.z); u0.s[3] = f2bf_bits(a00.w);
        u0.s[4] = f2bf_bits(a01.x); u0.s[5] = f2bf_bits(a01.y);
        u0.s[6] = f2bf_bits(a01.z); u0.s[7] = f2bf_bits(a01.w);
        u1.s[0] = f2bf_bits(a10.x); u1.s[1] = f2bf_bits(a10.y);
        u1.s[2] = f2bf_bits(a10.z); u1.s[3] = f2bf_bits(a10.w);
        u1.s[4] = f2bf_bits(a11.x); u1.s[5] = f2bf_bits(a11.y);
        u1.s[6] = f2bf_bits(a11.z); u1.s[7] = f2bf_bits(a11.w);
        *wA0 = u0.v; *wA1 = u1.v;
        *wB0 = b0;   *wB1 = b1;
        __syncthreads();

        // issue next tile's loads (no wait until next iter's cvt/write)
        if (it + 1 < HID / 32) {
            a00 = *(const float4*)gA0; a01 = *(const float4*)(gA0 + 4);
            a10 = *(const float4*)gA1; a11 = *(const float4*)(gA1 + 4);
            b0  = *(const uint4*)gB0;  b1  = *(const uint4*)gB1;
            gA0 += 32; gA1 += 32; gB0 += 32; gB1 += 32;
        }

        s8v af[4], bf[4];
#pragma unroll
        for (int i = 0; i < 4; ++i) af[i] = *(const s8v*)(pA + i * 16 * 32);
#pragma unroll
        for (int j = 0; j < 4; ++j) bf[j] = *(const s8v*)(pB + j * 16 * 32);
#pragma unroll
        for (int i = 0; i < 4; ++i)
#pragma unroll
            for (int j = 0; j < 4; ++j)
                acc[i][j] = __builtin_amdgcn_mfma_f32_16x16x32_bf16(
                    af[i], bf[j], acc[i][j], 0, 0, 0);
        __syncthreads();
    }

    if (isV) {
        // C/D layout: col = lane&15, row = quad*4 + reg  [m89/m91 verified]
#pragma unroll
        for (int i = 0; i < 4; ++i) {
            int row_b = m0 + wm * 64 + i * 16 + quad * 4;
#pragma unroll
            for (int j = 0; j < 4; ++j) {
                int col = n0 + wn * 64 + j * 16 + lm;
                float bsv = V1b[col];
#pragma unroll
                for (int reg = 0; reg < 4; ++reg) {
                    float v = acc[i][j][reg] + bsv;
                    C[(size_t)(row_b + reg) * HID + col] =
                        __float2bfloat16(fmaxf(v, 0.f));
                }
            }
        }
    } else {
        const int head = (n0 >> 6) + wn;      // wave covers one head's 64 cols
        float bj[4], rj[4];
#pragma unroll
        for (int j = 0; j < 4; ++j) {
            bj[j] = K1b[head * 64 + j * 16 + lm];
            rj[j] = RH[head * 64 + j * 16 + lm];
        }
#pragma unroll
        for (int i = 0; i < 4; ++i) {
            int row0 = m0 + wm * 64 + i * 16 + quad * 4;
#pragma unroll
            for (int reg = 0; reg < 4; ++reg) {
                float p = 0.f;
#pragma unroll
                for (int j = 0; j < 4; ++j)
                    p = fmaf(fmaxf(acc[i][j][reg] + bj[j], 0.f), rj[j], p);
                p += __shfl_xor(p, 1, 64);
                p += __shfl_xor(p, 2, 64);
                p += __shfl_xor(p, 4, 64);
                p += __shfl_xor(p, 8, 64);
                if (lm == 0) {
                    int row = row0 + reg;
                    int b = row >> 11, l = row & (L - 1);
                    dots[((b * H + head) << 11) + l] = p;
                    if (fabsf(p - 0.5f) < MARGIN) {
                        int idx = atomicAdd(fixcnt, 1);
                        if (idx < FIXCAP) fixlist[idx] = row * 16 + head;
                    }
                }
            }
        }
    }
}

// ---------------------------------------------------------------------------
// Fix-up: one block per flagged row (grid-stride over compacted list).
// ---------------------------------------------------------------------------
__global__ __launch_bounds__(256) void fixup_kernel(
    const float* __restrict__ hs,      // (BS*L, 768) fp32
    const float* __restrict__ W,       // (768, 768) K1_w fp32
    const float* __restrict__ bias,
    const float* __restrict__ RH,
    const int* __restrict__ fixlist,
    const int* __restrict__ fixcnt,
    float* __restrict__ dots)
{
    __shared__ float hrow[HID];
    __shared__ float psum[4][64];

    const int tid = threadIdx.x;
    const int n = min(*fixcnt, FIXCAP);

    for (int item = blockIdx.x; item < n; item += FIXGRID) {
        int packed = fixlist[item];
        int row = packed >> 4, head = packed & 15;
        int b = row >> 11, l = row & (L - 1);

#pragma unroll
        for (int i = 0; i < 3; ++i)
            hrow[tid + i * 256] = hs[(size_t)row * HID + tid + i * 256];
        __syncthreads();

        const int d = tid & 63, kq = tid >> 6;
        float a0 = 0.f, a1 = 0.f;
#pragma unroll 8
        for (int i = 0; i < 96; ++i) {
            int k = kq + i * 8;
            a0 = fmaf(W[(size_t)k * HID + head * 64 + d], hrow[k], a0);
            a1 = fmaf(W[(size_t)(k + 4) * HID + head * 64 + d], hrow[k + 4], a1);
        }
        psum[kq][d] = a0 + a1;
        __syncthreads();
        if (tid < 64) {
            float v = psum[0][tid] + psum[1][tid] + psum[2][tid] +
                      psum[3][tid] + bias[head * 64 + tid];
            v = fmaxf(v, 0.f) * RH[head * 64 + tid];
#pragma unroll
            for (int s = 1; s < 64; s <<= 1) v += __shfl_xor(v, s, 64);
            if (tid == 0) dots[((size_t)(b * H + head) << 11) + l] = v;
        }
        __syncthreads();
    }
}

// ---------------------------------------------------------------------------
// Scan: rank/select tables. Pg[bh][l] = # valid in [1..l]; Sg[bh][j] = j-th
// valid index (1-based).
// ---------------------------------------------------------------------------
__global__ __launch_bounds__(256) void scan_kernel(
    const float* __restrict__ dots,   // (BS*H, L)
    unsigned short* __restrict__ Pg,  // (BS*H, L)
    unsigned short* __restrict__ Sg)  // (BS*H, L)
{
    __shared__ int wsum[4];
    const int bh = blockIdx.x;
    const int tid = threadIdx.x;
    const int base = tid * 8;
    const int lane = tid & 63, w = tid >> 6;

    int m[8], c[8];
    int run = 0;
#pragma unroll
    for (int i = 0; i < 8; ++i) {
        int l = base + i;
        m[i] = (l >= 1 && dots[((size_t)bh << 11) + l] > 0.5f) ? 1 : 0;
        run += m[i];
        c[i] = run;
    }
    int sc = run;
#pragma unroll
    for (int s = 1; s < 64; s <<= 1) {
        int v = __shfl_up(sc, s, 64);
        if (lane >= s) sc += v;
    }
    if (lane == 63) wsum[w] = sc;
    __syncthreads();
    int woff = 0;
    for (int i = 0; i < 4; ++i) if (i < w) woff += wsum[i];
    const int ex = woff + sc - run;

    union { unsigned short s[8]; uint4 q; } up;
#pragma unroll
    for (int i = 0; i < 8; ++i) {
        int pc = ex + c[i];
        up.s[i] = (unsigned short)pc;
        if (m[i]) Sg[((size_t)bh << 11) + pc] = (unsigned short)(base + i);
    }
    *(uint4*)&Pg[((size_t)bh << 11) + base] = up.q;
}

// ---------------------------------------------------------------------------
// Gather v3: block = (ltile of 128, bh); stage the tile's contiguous S-range
// of V1 row-slices into LDS once, reconstruct fm/bm slots from P on the fly.
// ---------------------------------------------------------------------------
__global__ __launch_bounds__(256) void gather_kernel(
    const __hip_bfloat16* __restrict__ V1,   // (8192, 768) bf16
    const unsigned short* __restrict__ Pg,
    const unsigned short* __restrict__ Sg,
    const float* __restrict__ bw,            // (H, 2R)
    float* __restrict__ out)                 // (8192, 768) fp32
{
    __shared__ __hip_bfloat16 Vs[161 * 72];  // slot pitch 144 B (16B aligned)
    __shared__ unsigned short Ptile[129];    // P[l0-1 .. l0+127]
    __shared__ float sw[2 * R];
    __shared__ int sT;

    const int bh = blockIdx.y;
    const int b = bh / H, h = bh % H;
    const int l0 = blockIdx.x * 128;
    const int tid = threadIdx.x;

    if (tid < 129) {
        int l = l0 - 1 + tid;
        Ptile[tid] = (l >= 0) ? Pg[((size_t)bh << 11) + l] : (unsigned short)0;
    } else if (tid < 129 + 2 * R) {
        sw[tid - 129] = bw[h * (2 * R) + (tid - 129)];
    } else if (tid == 200) {
        sT = Pg[((size_t)bh << 11) + (L - 1)];
    }
    __syncthreads();

    const int T = sT;
    const int a = max(1, (int)Ptile[1] - (R - 1));
    const int bj = min(T, (int)Ptile[127] + R);
    const int nr = max(0, bj - a + 1);       // <= 158

    const __hip_bfloat16* Vbase = V1 + (size_t)b * L * HID + h * HD;
    for (int it = tid; it < (nr + 1) * 8; it += 256) {
        int slot = it >> 3, oct = it & 7;
        int row = slot ? (int)Sg[((size_t)bh << 11) + a + slot - 1] : 0;
        *(uint4*)&Vs[slot * 72 + oct * 8] =
            *(const uint4*)&Vbase[(size_t)row * HID + oct * 8];
    }
    __syncthreads();

    const int d8 = tid & 7, lg = tid >> 3;   // lg 0..31

#pragma unroll
    for (int li = 0; li < 4; ++li) {
        int ll = lg + 32 * li;               // 0..127
        int l = l0 + ll;
        int Pl = Ptile[1 + ll], Plm1 = Ptile[ll];
        bool lpos = (l >= 1);
        float acc0 = 0.f, acc1 = 0.f, acc2 = 0.f, acc3 = 0.f;
        float acc4 = 0.f, acc5 = 0.f, acc6 = 0.f, acc7 = 0.f;
#pragma unroll
        for (int r = 0; r < 2 * R; ++r) {
            int j, ok;
            if (r < R) { j = Pl - r;             ok = lpos && (j >= 1); }
            else       { j = Plm1 + 1 + (r - R); ok = lpos && (j <= T); }
            int slot = ok ? (j - a + 1) : 0;
            float wv = sw[r];
            uint4 uv = *(const uint4*)&Vs[slot * 72 + d8 * 8];
            acc0 = fmaf(wv, __uint_as_float(uv.x << 16), acc0);
            acc1 = fmaf(wv, __uint_as_float(uv.x & 0xffff0000u), acc1);
            acc2 = fmaf(wv, __uint_as_float(uv.y << 16), acc2);
            acc3 = fmaf(wv, __uint_as_float(uv.y & 0xffff0000u), acc3);
            acc4 = fmaf(wv, __uint_as_float(uv.z << 16), acc4);
            acc5 = fmaf(wv, __uint_as_float(uv.z & 0xffff0000u), acc5);
            acc6 = fmaf(wv, __uint_as_float(uv.w << 16), acc6);
            acc7 = fmaf(wv, __uint_as_float(uv.w & 0xffff0000u), acc7);
        }
        float* op = &out[((size_t)b * L + l) * HID + h * HD + d8 * 8];
        float4 o0, o1;
        o0.x = acc0; o0.y = acc1; o0.z = acc2; o0.w = acc3;
        o1.x = acc4; o1.y = acc5; o1.z = acc6; o1.w = acc7;
        *(float4*)op = o0;
        *(float4*)(op + 4) = o1;
    }
}

extern "C" void kernel_launch(void* const* d_in, const int* in_sizes, int n_in,
                              void* d_out, int out_size, void* d_ws, size_t ws_size,
                              hipStream_t stream) {
    const float* hs  = (const float*)d_in[0];
    const float* K1w = (const float*)d_in[1];
    const float* K1b = (const float*)d_in[2];
    const float* V1w = (const float*)d_in[3];
    const float* V1b = (const float*)d_in[4];
    const float* RH  = (const float*)d_in[5];
    const float* bw  = (const float*)d_in[6];
    float* out = (float*)d_out;

    // workspace layout (total ~15.8 MB)
    char* ws = (char*)d_ws;
    __hip_bfloat16* WtV = (__hip_bfloat16*)ws;                 // 1,179,648
    __hip_bfloat16* WtK = (__hip_bfloat16*)(ws + 1179648);     // 1,179,648
    __hip_bfloat16* V1  = (__hip_bfloat16*)(ws + 2359296);     // 12,582,912
    float* dots = (float*)(ws + 14942208);                     //   393,216
    unsigned short* Pg = (unsigned short*)(ws + 15335424);     //   196,608
    unsigned short* Sg = (unsigned short*)(ws + 15532032);     //   196,608
    int* fixlist = (int*)(ws + 15728640);                      //    65,536
    int* fixcnt  = (int*)(ws + 15794176);                      //         4

    prep_kernel<<<2 * 24 * 24, 256, 0, stream>>>(K1w, V1w, WtK, WtV, fixcnt);
    gemm_fused<<<dim3(BS * L / 128, 12), 256, 0, stream>>>(
        hs, WtK, WtV, K1b, V1b, RH, dots, fixlist, fixcnt, V1);
    fixup_kernel<<<FIXGRID, 256, 0, stream>>>(hs, K1w, K1b, RH, fixlist, fixcnt, dots);
    scan_kernel<<<BS * H, 256, 0, stream>>>(dots, Pg, Sg);
    gather_kernel<<<dim3(L / 128, BS * H), 256, 0, stream>>>(V1, Pg, Sg, bw, out);
}